// Round 16
// baseline (131.205 us; speedup 1.0000x reference)
//
#include <hip/hip_runtime.h>

#define DM 1024
#define NH 16
#define DKq 64
#define BB 2
#define SS 2048
#define MTOT 4096

// K2 = log2(e)/sqrt(64); folded into Qt at projection time.
#define K2f 0.18033688011112042f
#define IK2f 5.545177444479562f

typedef __attribute__((ext_vector_type(4))) float f32x4;
typedef __attribute__((ext_vector_type(16))) float f32x16;
typedef __attribute__((ext_vector_type(8))) short s16x8;
typedef __attribute__((ext_vector_type(4))) short s16x4;
typedef __attribute__((ext_vector_type(4))) unsigned short u16x4;

__device__ __forceinline__ unsigned short f2bf(float f) {
    unsigned u = __float_as_uint(f);
    u += 0x7fff + ((u >> 16) & 1);   // RNE
    return (unsigned short)(u >> 16);
}

__device__ __forceinline__ float bf2f(unsigned short x) {
    return __uint_as_float((unsigned)x << 16);
}

__device__ __forceinline__ s16x8 cvt8(f32x4 a, f32x4 b) {
    s16x8 r;
    r[0] = (short)f2bf(a[0]); r[1] = (short)f2bf(a[1]);
    r[2] = (short)f2bf(a[2]); r[3] = (short)f2bf(a[3]);
    r[4] = (short)f2bf(b[0]); r[5] = (short)f2bf(b[1]);
    r[6] = (short)f2bf(b[2]); r[7] = (short)f2bf(b[3]);
    return r;
}

// single-op truncation pack: low16 = a[31:16], high16 = b[31:16]  (v_perm_b32)
__device__ __forceinline__ unsigned pkp(float a, float b) {
    return __builtin_amdgcn_perm(__float_as_uint(b), __float_as_uint(a), 0x07060302u);
}

__device__ __forceinline__ void gload_lds16(const void* g, void* l) {
    __builtin_amdgcn_global_load_lds(
        (const __attribute__((address_space(1))) unsigned int*)g,
        (__attribute__((address_space(3))) unsigned int*)l,
        16, 0, 0);
}

// ---------------------------------------------------------------------------
// Kernel 0: fp32 -> bf16 conversion pass (memory-bound).  (unchanged)
// ---------------------------------------------------------------------------
__global__ __launch_bounds__(256)
void cvt_kernel(const float* __restrict__ s0, const float* __restrict__ s1,
                const float* __restrict__ s2, const float* __restrict__ s3,
                const float* __restrict__ s4, const float* __restrict__ s5,
                const float* __restrict__ s6,
                unsigned short* __restrict__ Xb, unsigned short* __restrict__ Wb)
{
    const int seg = blockIdx.y;
    const float* src;
    unsigned short* dst;
    int n;
    if (seg < 3) {
        src = (seg == 0) ? s0 : (seg == 1) ? s1 : s2;
        dst = Xb + (size_t)seg * (MTOT * DM);
        n = MTOT * DM;
    } else {
        src = (seg == 3) ? s3 : (seg == 4) ? s4 : (seg == 5) ? s5 : s6;
        dst = Wb + (size_t)(seg - 3) * (DM * DM);
        n = DM * DM;
    }
    const int stride = gridDim.x * 256;
    for (int i = blockIdx.x * 256 + threadIdx.x; i * 8 < n; i += stride) {
        f32x4 a = *(const f32x4*)(src + (size_t)i * 8);
        f32x4 b = *(const f32x4*)(src + (size_t)i * 8 + 4);
        *(s16x8*)(dst + (size_t)i * 8) = cvt8(a, b);
    }
}

// ---------------------------------------------------------------------------
// Kernel 1: QKV projections, bf16 GEMM, XCD-swizzled, launch_bounds(256,3),
// BK=32 double-buffer.
// z=0 -> Qt [B,H,DK,S] TRANSPOSED, scaled by K2 (vectorized u16x4 stores)
// z=1 -> Kh [B,H,S,DK]
// z=2 -> Vt [B,H,DK,S] with kv bits 2<->3 swapped
// ---------------------------------------------------------------------------
__global__ __launch_bounds__(256, 3)
void proj_kernel(const unsigned short* __restrict__ Xb,
                 const unsigned short* __restrict__ Wb,
                 const float* __restrict__ bq, const float* __restrict__ bk,
                 const float* __restrict__ bv,
                 unsigned short* __restrict__ Qt, unsigned short* __restrict__ Kh,
                 unsigned short* __restrict__ Vt)
{
    // XCD-chunked swizzle: 768 wgs, 96 per XCD, contiguous (z,y) per chunk
    const int bid = blockIdx.x;
    const int t   = (bid & 7) * 96 + (bid >> 3);
    const int z   = t >> 8;
    const int ty  = (t >> 3) & 31;
    const int tx  = t & 7;

    const unsigned short* X = Xb + (size_t)z * (MTOT * DM);
    const unsigned short* W = Wb + (size_t)z * (DM * DM);
    const float* bias = (z == 0) ? bq : (z == 1) ? bk : bv;

    const int m0 = ty * 128;
    const int n0 = tx * 128;
    const int tid  = threadIdx.x;
    const int lane = tid & 63;
    const int w    = tid >> 6;
    const int wm   = w >> 1, wn = w & 1;

    __shared__ __align__(16) short lA[2][128 * 32];   // 8KB each
    __shared__ __align__(16) short lB[2][128 * 32];

    f32x4 acc[4][4];
#pragma unroll
    for (int i = 0; i < 4; i++)
#pragma unroll
        for (int j = 0; j < 4; j++) acc[i][j] = (f32x4)(0.f);

    // staging: chunk c = w*2+p covers rows c*16..c*16+15; lane -> (row,slot)
    const int srow16 = lane >> 2;     // 0..15
    const int scg    = lane & 3;      // slot 0..3

#define PSTAGE(BUF, KC) {                                                     \
    const int k0_ = (KC) * 32;                                                \
    _Pragma("unroll")                                                         \
    for (int p = 0; p < 2; ++p) {                                             \
        int c = w * 2 + p;                                                    \
        int row = c * 16 + srow16;                                            \
        int kc = scg ^ ((row >> 1) & 3);                                      \
        gload_lds16(X + (size_t)(m0 + row) * DM + k0_ + kc * 8,               \
                    (char*)lA[BUF] + c * 1024);                               \
        gload_lds16(W + (size_t)(n0 + row) * DM + k0_ + kc * 8,               \
                    (char*)lB[BUF] + c * 1024);                               \
    } }

#define PCOMPUTE(BUF) {                                                       \
    s16x8 af[4], bf[4];                                                       \
    const int kq = lane >> 4;                                                 \
    _Pragma("unroll")                                                         \
    for (int i = 0; i < 4; i++) {                                             \
        int row = wm * 64 + i * 16 + (lane & 15);                             \
        int slot = kq ^ ((row >> 1) & 3);                                     \
        af[i] = *(const s16x8*)((const char*)lA[BUF] + row * 64 + slot * 16); \
    }                                                                         \
    _Pragma("unroll")                                                         \
    for (int i = 0; i < 4; i++) {                                             \
        int row = wn * 64 + i * 16 + (lane & 15);                             \
        int slot = kq ^ ((row >> 1) & 3);                                     \
        bf[i] = *(const s16x8*)((const char*)lB[BUF] + row * 64 + slot * 16); \
    }                                                                         \
    _Pragma("unroll")                                                         \
    for (int i = 0; i < 4; i++)                                               \
        _Pragma("unroll")                                                     \
        for (int j = 0; j < 4; j++)                                           \
            acc[i][j] = __builtin_amdgcn_mfma_f32_16x16x32_bf16(              \
                af[i], bf[j], acc[i][j], 0, 0, 0);                            \
    }

    PSTAGE(0, 0);
    __syncthreads();
    for (int kp = 0; kp < 16; ++kp) {
        const int k2 = kp * 2;
        if (k2 + 1 < 32) PSTAGE(1, k2 + 1);
        PCOMPUTE(0);
        __syncthreads();
        if (k2 + 2 < 32) PSTAGE(0, k2 + 2);
        PCOMPUTE(1);
        __syncthreads();
    }
#undef PSTAGE
#undef PCOMPUTE

#pragma unroll
    for (int i = 0; i < 4; i++) {
#pragma unroll
        for (int j = 0; j < 4; j++) {
            int rg0 = m0 + wm * 64 + i * 16 + 4 * (lane >> 4);
            int cg  = n0 + wn * 64 + j * 16 + (lane & 15);
            int b = rg0 >> 11, s0 = rg0 & 2047, h = cg >> 6, d = cg & 63;
            float bv_ = bias[cg];
            if (z == 2) {
                // kv column permute: swap bits 2<->3 (PV fragment order)
                int s0p = (s0 & ~12) | ((s0 & 4) << 1) | ((s0 & 8) >> 1);
                u16x4 st;
#pragma unroll
                for (int e = 0; e < 4; e++) st[e] = f2bf(acc[i][j][e] + bv_);
                *(u16x4*)&Vt[(((size_t)(b * NH + h)) * DKq + d) * SS + s0p] = st;
            } else if (z == 0) {
                // Qt [B,H,DK,S], scaled by K2: vectorized along s
                u16x4 st;
#pragma unroll
                for (int e = 0; e < 4; e++) st[e] = f2bf((acc[i][j][e] + bv_) * K2f);
                *(u16x4*)&Qt[(((size_t)(b * NH + h)) * DKq + d) * SS + s0] = st;
            } else {
#pragma unroll
                for (int e = 0; e < 4; e++)
                    Kh[(((size_t)(b * NH + h)) * SS + s0 + e) * DKq + d] =
                        f2bf(acc[i][j][e] + bv_);
            }
        }
    }
}

// ---------------------------------------------------------------------------
// Kernel 2: flash attention, 32x32x16, KVBLK=128 windows, VALU row-sum.
// Q read from transposed Qt [B,H,DK,S] (scalar gather, once per block).
// ---------------------------------------------------------------------------
__device__ __forceinline__ void attn_tile32(
    const char* __restrict__ lkc, const char* __restrict__ lvc,
    const s16x8* aq, int l31, int hi,
    f32x16& o0, f32x16& o1, float& rs)
{
    f32x16 s0 = (f32x16)(0.f), s1 = (f32x16)(0.f);
    const int sw = (l31 & 7) << 4;
    __builtin_amdgcn_s_setprio(1);
#pragma unroll
    for (int kkd = 0; kkd < 4; kkd++) {
        const int byte = (32 * kkd + 16 * hi) ^ sw;
        s16x8 ak0 = *(const s16x8*)(lkc + l31 * 128 + byte);
        s0 = __builtin_amdgcn_mfma_f32_32x32x16_bf16(ak0, aq[kkd], s0, 0, 0, 0);
        s16x8 ak1 = *(const s16x8*)(lkc + (32 + l31) * 128 + byte);
        s1 = __builtin_amdgcn_mfma_f32_32x32x16_bf16(ak1, aq[kkd], s1, 0, 0, 0);
    }
    __builtin_amdgcn_s_setprio(0);

    // P = exp2(s); per-lane partial row-sum (this lane's hi half of kv rows)
    float r0 = 0.f, r1 = 0.f;
#pragma unroll
    for (int r = 0; r < 16; r++) {
        float p0 = __builtin_amdgcn_exp2f(s0[r]);
        float p1 = __builtin_amdgcn_exp2f(s1[r]);
        s0[r] = p0; s1[r] = p1;
        r0 += p0; r1 += p1;
    }
    rs += r0 + r1;

    __builtin_amdgcn_s_setprio(1);
#pragma unroll
    for (int jb = 0; jb < 2; jb++) {
#pragma unroll
        for (int u = 0; u < 2; u++) {
            const int t = 2 * jb + u;
            union { unsigned uu[4]; s16x8 v; } bp;
            if (jb == 0) {
                bp.uu[0] = pkp(s0[8*u+0], s0[8*u+1]);
                bp.uu[1] = pkp(s0[8*u+2], s0[8*u+3]);
                bp.uu[2] = pkp(s0[8*u+4], s0[8*u+5]);
                bp.uu[3] = pkp(s0[8*u+6], s0[8*u+7]);
            } else {
                bp.uu[0] = pkp(s1[8*u+0], s1[8*u+1]);
                bp.uu[1] = pkp(s1[8*u+2], s1[8*u+3]);
                bp.uu[2] = pkp(s1[8*u+4], s1[8*u+5]);
                bp.uu[3] = pkp(s1[8*u+6], s1[8*u+7]);
            }
            const int vbyte = (32 * t + 16 * hi) ^ sw;
            s16x8 av0 = *(const s16x8*)(lvc + l31 * 128 + vbyte);
            o0 = __builtin_amdgcn_mfma_f32_32x32x16_bf16(av0, bp.v, o0, 0, 0, 0);
            s16x8 av1 = *(const s16x8*)(lvc + (32 + l31) * 128 + vbyte);
            o1 = __builtin_amdgcn_mfma_f32_32x32x16_bf16(av1, bp.v, o1, 0, 0, 0);
        }
    }
    __builtin_amdgcn_s_setprio(0);
}

__global__ __launch_bounds__(256)
void attn_kernel(const unsigned short* __restrict__ Qt,
                 const unsigned short* __restrict__ Kh,
                 const unsigned short* __restrict__ Vt,
                 unsigned short* __restrict__ Ctx)
{
    // XCD-chunked swizzle: 512 wgs, 64 per XCD -> 4 heads' K/V per XCD L2
    const int bid = blockIdx.x;
    const int tt  = (bid & 7) * 64 + (bid >> 3);
    const int bh  = tt >> 4;
    const int q0  = (tt & 15) * 128;

    const int tid = threadIdx.x, lane = tid & 63, w = tid >> 6;
    const int b = bh >> 4, h = bh & 15;
    const int l31 = lane & 31;
    const int hi  = lane >> 5;

    // each buffer = TWO 64-kv sub-tiles, concatenated (16KB K + 16KB V)
    __shared__ __align__(16) short lKs[2][128 * 64];
    __shared__ __align__(16) short lVs[2][128 * 64];

    const size_t qk_base = (size_t)bh * SS * DKq;
    const size_t vt_base = (size_t)bh * DKq * SS;

    // Q B-frag from transposed Qt: aq[kkd][j] = Qt[bh][16*kkd+8*hi+j][qrow]
    s16x8 aq[4];
    const int qrow = q0 + 32 * w + l31;
    {
        const unsigned short* qp = Qt + vt_base + (size_t)(8 * hi) * SS + qrow;
#pragma unroll
        for (int kkd = 0; kkd < 4; kkd++) {
#pragma unroll
            for (int j = 0; j < 8; j++)
                aq[kkd][j] = (short)qp[(size_t)(16 * kkd + j) * SS];
        }
    }

    f32x16 o0 = (f32x16)(0.f), o1 = (f32x16)(0.f);
    float rs = 0.f;

    // staging geometry (global_load_lds, pre-swizzled global source)
    const int lrow = lane >> 3;           // 0..7
    const int lcg  = (lane & 7) ^ lrow;   // inverse-swizzled col chunk

    // stage 128 kv rows (two 64-kv sub-tiles) per buffer; 4 chunks/thread
#define STAGE(BUF, KV0) {                                                     \
    char* dk = (char*)lKs[BUF]; char* dv = (char*)lVs[BUF];                   \
    _Pragma("unroll")                                                         \
    for (int p = 0; p < 4; ++p) {                                             \
        int c = 4 * w + p;            /* 0..15 */                             \
        int half = c >> 3, cc = c & 7;                                        \
        gload_lds16(Kh + qk_base + (size_t)((KV0) + c * 8 + lrow) * DKq + lcg * 8, \
                    dk + c * 1024);                                           \
        gload_lds16(Vt + vt_base + (size_t)(cc * 8 + lrow) * SS                \
                        + (KV0) + half * 64 + lcg * 8,                        \
                    dv + c * 1024);                                           \
    } }

    STAGE(0, 0);
    __syncthreads();

    for (int th = 0; th < 8; ++th) {
        const int T0 = th * 2;          // 128-kv tile index
        STAGE(1, (T0 + 1) * 128);
        attn_tile32((const char*)lKs[0], (const char*)lVs[0], aq, l31, hi, o0, o1, rs);
        attn_tile32((const char*)lKs[0] + 8192, (const char*)lVs[0] + 8192, aq, l31, hi, o0, o1, rs);
        __syncthreads();
        if (T0 + 2 < 16) STAGE(0, (T0 + 2) * 128);
        attn_tile32((const char*)lKs[1], (const char*)lVs[1], aq, l31, hi, o0, o1, rs);
        attn_tile32((const char*)lKs[1] + 8192, (const char*)lVs[1] + 8192, aq, l31, hi, o0, o1, rs);
        __syncthreads();
    }
#undef STAGE

    // epilogue: combine the two hi halves' partial sums, normalize, store
    rs += __shfl_xor(rs, 32);
    const float inv = 1.0f / rs;
    unsigned short* crow = Ctx + ((size_t)(b * SS + qrow)) * DM + h * 64;
#pragma unroll
    for (int db = 0; db < 2; db++) {
#pragma unroll
        for (int v = 0; v < 4; v++) {
            u16x4 st;
#pragma unroll
            for (int e = 0; e < 4; e++) {
                float x = (db == 0) ? o0[4 * v + e] : o1[4 * v + e];
                st[e] = f2bf(x * inv);
            }
            *(u16x4*)(crow + 32 * db + 8 * v + 4 * hi) = st;
        }
    }
}

// ---------------------------------------------------------------------------
// Kernel 3: out = Ctx @ Wo^T + bo + residual(Qt * 1/K2)  (fp32, into d_out)
// XCD-swizzled + 2-phase dbuf staging; residual now a vectorized u16x4 load.
// ---------------------------------------------------------------------------
__global__ __launch_bounds__(256)
void outproj_kernel(const unsigned short* __restrict__ Ctx,
                    const unsigned short* __restrict__ Wo,
                    const float* __restrict__ bo,
                    const unsigned short* __restrict__ Qt,
                    float* __restrict__ Out)
{
    // XCD-chunked swizzle: 256 wgs, 32 per XCD
    const int bid = blockIdx.x;
    const int t   = (bid & 7) * 32 + (bid >> 3);
    const int ty  = t >> 3;
    const int tx  = t & 7;

    const int m0 = ty * 128;
    const int n0 = tx * 128;
    const int tid = threadIdx.x, lane = tid & 63, w = tid >> 6;
    const int wm = w >> 1, wn = w & 1;

    __shared__ __align__(16) short lA[2][128 * 64];
    __shared__ __align__(16) short lB[2][128 * 64];

    f32x4 acc[4][4];
#pragma unroll
    for (int i = 0; i < 4; i++)
#pragma unroll
        for (int j = 0; j < 4; j++) acc[i][j] = (f32x4)(0.f);

    const int lrow = lane >> 3;
    const int lcg  = (lane & 7) ^ lrow;

#define PSTAGE(BUF, KT) {                                                     \
    const int k0_ = (KT) * 64;                                                \
    _Pragma("unroll")                                                         \
    for (int p = 0; p < 4; ++p) {                                             \
        int c = w * 4 + p;                                                    \
        int row = c * 8 + lrow;                                               \
        gload_lds16(Ctx + (size_t)(m0 + row) * DM + k0_ + lcg * 8,            \
                    (char*)lA[BUF] + c * 1024);                               \
        gload_lds16(Wo + (size_t)(n0 + row) * DM + k0_ + lcg * 8,             \
                    (char*)lB[BUF] + c * 1024);                               \
    } }

#define PCOMPUTE(BUF) {                                                       \
    _Pragma("unroll")                                                         \
    for (int kk = 0; kk < 2; ++kk) {                                          \
        s16x8 af[4], bf[4];                                                   \
        _Pragma("unroll")                                                     \
        for (int i = 0; i < 4; i++) {                                         \
            int row = wm * 64 + i * 16 + (lane & 15);                         \
            int byte = (kk * 64 + 16 * (lane >> 4)) ^ ((row & 7) << 4);       \
            af[i] = *(const s16x8*)((const char*)lA[BUF] + row * 128 + byte); \
        }                                                                     \
        _Pragma("unroll")                                                     \
        for (int i = 0; i < 4; i++) {                                         \
            int row = wn * 64 + i * 16 + (lane & 15);                         \
            int byte = (kk * 64 + 16 * (lane >> 4)) ^ ((row & 7) << 4);       \
            bf[i] = *(const s16x8*)((const char*)lB[BUF] + row * 128 + byte); \
        }                                                                     \
        _Pragma("unroll")                                                     \
        for (int i = 0; i < 4; i++)                                           \
            _Pragma("unroll")                                                 \
            for (int j = 0; j < 4; j++)                                       \
                acc[i][j] = __builtin_amdgcn_mfma_f32_16x16x32_bf16(          \
                    af[i], bf[j], acc[i][j], 0, 0, 0);                        \
    } }

    PSTAGE(0, 0);
    __syncthreads();
    for (int kh = 0; kh < 8; ++kh) {
        const int k0 = kh * 2;
        if (k0 + 1 < 16) PSTAGE(1, k0 + 1);
        PCOMPUTE(0);
        __syncthreads();
        if (k0 + 2 < 16) PSTAGE(0, k0 + 2);
        PCOMPUTE(1);
        __syncthreads();
    }
#undef PSTAGE
#undef PCOMPUTE

#pragma unroll
    for (int i = 0; i < 4; i++) {
#pragma unroll
        for (int j = 0; j < 4; j++) {
            int rg0 = m0 + wm * 64 + i * 16 + 4 * (lane >> 4);
            int cg  = n0 + wn * 64 + j * 16 + (lane & 15);
            int b = rg0 >> 11, s0 = rg0 & 2047, h = cg >> 6, d = cg & 63;
            float bo_ = bo[cg];
            u16x4 rq = *(const u16x4*)&Qt[(((size_t)(b * NH + h)) * DKq + d) * SS + s0];
#pragma unroll
            for (int e = 0; e < 4; e++) {
                Out[(size_t)(rg0 + e) * DM + cg] =
                    __builtin_fmaf(bf2f(rq[e]), IK2f, acc[i][j][e] + bo_);
            }
        }
    }
}

// ---------------------------------------------------------------------------
// Kernel 4: in-place LayerNorm over rows of Out [4096][1024]  (unchanged)
// ---------------------------------------------------------------------------
__global__ __launch_bounds__(256)
void ln_kernel(float* __restrict__ Out, const float* __restrict__ gamma,
               const float* __restrict__ beta)
{
    const int row = blockIdx.x;
    float* rp = Out + (size_t)row * DM;
    const int tid = threadIdx.x;

    f32x4 x = *(const f32x4*)(rp + tid * 4);
    float s  = x[0] + x[1] + x[2] + x[3];
    float sq = x[0] * x[0] + x[1] * x[1] + x[2] * x[2] + x[3] * x[3];
#pragma unroll
    for (int off = 1; off < 64; off <<= 1) {
        s  += __shfl_xor(s, off);
        sq += __shfl_xor(sq, off);
    }
    __shared__ float ps[4], pq[4];
    const int w = tid >> 6;
    if ((tid & 63) == 0) { ps[w] = s; pq[w] = sq; }
    __syncthreads();
    float ts = ps[0] + ps[1] + ps[2] + ps[3];
    float tq = pq[0] + pq[1] + pq[2] + pq[3];
    float mu  = ts * (1.f / 1024.f);
    float var = tq * (1.f / 1024.f) - mu * mu;
    float rst = rsqrtf(var + 1e-5f);

    f32x4 g  = *(const f32x4*)(gamma + tid * 4);
    f32x4 bt = *(const f32x4*)(beta + tid * 4);
    f32x4 y;
#pragma unroll
    for (int e = 0; e < 4; e++) y[e] = (x[e] - mu) * rst * g[e] + bt[e];
    *(f32x4*)(rp + tid * 4) = y;
}

// ---------------------------------------------------------------------------
extern "C" void kernel_launch(void* const* d_in, const int* in_sizes, int n_in,
                              void* d_out, int out_size, void* d_ws, size_t ws_size,
                              hipStream_t stream)
{
    const float* query = (const float*)d_in[0];
    const float* key   = (const float*)d_in[1];
    const float* value = (const float*)d_in[2];
    const float* Wq = (const float*)d_in[3];
    const float* bq = (const float*)d_in[4];
    const float* Wk = (const float*)d_in[5];
    const float* bk = (const float*)d_in[6];
    const float* Wv = (const float*)d_in[7];
    const float* bv = (const float*)d_in[8];
    const float* Wo = (const float*)d_in[9];
    const float* bo = (const float*)d_in[10];
    const float* gamma = (const float*)d_in[11];
    const float* beta  = (const float*)d_in[12];

    char* ws = (char*)d_ws;
    // layout (56 MB total):
    //   Xb  @ 0      : 3 x 8MB bf16 activations (dead after proj)
    //   Wb  @ 24MB   : 4 x 2MB bf16 weights (q,k,v,o)
    //   Qt  @ 32MB, Kh @ 40MB, Vt @ 48MB : 8MB each
    //   Ctx @ 0      : 8MB, overlays dead Xb[query]
    unsigned short* Xb  = (unsigned short*)(ws);
    unsigned short* Wb  = (unsigned short*)(ws + (24u << 20));
    unsigned short* Qt  = (unsigned short*)(ws + (32u << 20));
    unsigned short* Kh  = (unsigned short*)(ws + (40u << 20));
    unsigned short* Vt  = (unsigned short*)(ws + (48u << 20));
    unsigned short* Ctx = (unsigned short*)(ws);
    float* Out = (float*)d_out;

    cvt_kernel<<<dim3(256, 7), 256, 0, stream>>>(query, key, value,
                                                 Wq, Wk, Wv, Wo, Xb, Wb);
    proj_kernel<<<768, 256, 0, stream>>>(Xb, Wb, bq, bk, bv, Qt, Kh, Vt);
    attn_kernel<<<512, 256, 0, stream>>>(Qt, Kh, Vt, Ctx);
    outproj_kernel<<<256, 256, 0, stream>>>(Ctx, Wb + 3u * DM * DM, bo, Qt, Out);
    ln_kernel<<<4096, 256, 0, stream>>>(Out, gamma, beta);
}

// Round 17
// 129.079 us; speedup vs baseline: 1.0165x; 1.0165x over previous
//
#include <hip/hip_runtime.h>

#define DM 1024
#define NH 16
#define DKq 64
#define BB 2
#define SS 2048
#define MTOT 4096

// K2 = log2(e)/sqrt(64); folded into Qh at projection time.
#define K2f 0.18033688011112042f
#define IK2f 5.545177444479562f

typedef __attribute__((ext_vector_type(4))) float f32x4;
typedef __attribute__((ext_vector_type(16))) float f32x16;
typedef __attribute__((ext_vector_type(8))) short s16x8;
typedef __attribute__((ext_vector_type(4))) short s16x4;
typedef __attribute__((ext_vector_type(4))) unsigned short u16x4;

__device__ __forceinline__ unsigned short f2bf(float f) {
    unsigned u = __float_as_uint(f);
    u += 0x7fff + ((u >> 16) & 1);   // RNE
    return (unsigned short)(u >> 16);
}

__device__ __forceinline__ float bf2f(unsigned short x) {
    return __uint_as_float((unsigned)x << 16);
}

__device__ __forceinline__ s16x8 cvt8(f32x4 a, f32x4 b) {
    s16x8 r;
    r[0] = (short)f2bf(a[0]); r[1] = (short)f2bf(a[1]);
    r[2] = (short)f2bf(a[2]); r[3] = (short)f2bf(a[3]);
    r[4] = (short)f2bf(b[0]); r[5] = (short)f2bf(b[1]);
    r[6] = (short)f2bf(b[2]); r[7] = (short)f2bf(b[3]);
    return r;
}

// single-op truncation pack: low16 = a[31:16], high16 = b[31:16]  (v_perm_b32)
__device__ __forceinline__ unsigned pkp(float a, float b) {
    return __builtin_amdgcn_perm(__float_as_uint(b), __float_as_uint(a), 0x07060302u);
}

__device__ __forceinline__ void gload_lds16(const void* g, void* l) {
    __builtin_amdgcn_global_load_lds(
        (const __attribute__((address_space(1))) unsigned int*)g,
        (__attribute__((address_space(3))) unsigned int*)l,
        16, 0, 0);
}

// ---------------------------------------------------------------------------
// Kernel 0: fp32 -> bf16 conversion pass (memory-bound).
// ---------------------------------------------------------------------------
__global__ __launch_bounds__(256)
void cvt_kernel(const float* __restrict__ s0, const float* __restrict__ s1,
                const float* __restrict__ s2, const float* __restrict__ s3,
                const float* __restrict__ s4, const float* __restrict__ s5,
                const float* __restrict__ s6,
                unsigned short* __restrict__ Xb, unsigned short* __restrict__ Wb)
{
    const int seg = blockIdx.y;
    const float* src;
    unsigned short* dst;
    int n;
    if (seg < 3) {
        src = (seg == 0) ? s0 : (seg == 1) ? s1 : s2;
        dst = Xb + (size_t)seg * (MTOT * DM);
        n = MTOT * DM;
    } else {
        src = (seg == 3) ? s3 : (seg == 4) ? s4 : (seg == 5) ? s5 : s6;
        dst = Wb + (size_t)(seg - 3) * (DM * DM);
        n = DM * DM;
    }
    const int stride = gridDim.x * 256;
    for (int i = blockIdx.x * 256 + threadIdx.x; i * 8 < n; i += stride) {
        f32x4 a = *(const f32x4*)(src + (size_t)i * 8);
        f32x4 b = *(const f32x4*)(src + (size_t)i * 8 + 4);
        *(s16x8*)(dst + (size_t)i * 8) = cvt8(a, b);
    }
}

// ---------------------------------------------------------------------------
// Kernel 1: QKV projections, bf16 GEMM, XCD-swizzled, launch_bounds(256,3),
// BK=32 double-buffer.
// ---------------------------------------------------------------------------
__global__ __launch_bounds__(256, 3)
void proj_kernel(const unsigned short* __restrict__ Xb,
                 const unsigned short* __restrict__ Wb,
                 const float* __restrict__ bq, const float* __restrict__ bk,
                 const float* __restrict__ bv,
                 unsigned short* __restrict__ Qh, unsigned short* __restrict__ Kh,
                 unsigned short* __restrict__ Vt)
{
    // XCD-chunked swizzle: 768 wgs, 96 per XCD, contiguous (z,y) per chunk
    const int bid = blockIdx.x;
    const int t   = (bid & 7) * 96 + (bid >> 3);
    const int z   = t >> 8;
    const int ty  = (t >> 3) & 31;
    const int tx  = t & 7;

    const unsigned short* X = Xb + (size_t)z * (MTOT * DM);
    const unsigned short* W = Wb + (size_t)z * (DM * DM);
    const float* bias = (z == 0) ? bq : (z == 1) ? bk : bv;

    const int m0 = ty * 128;
    const int n0 = tx * 128;
    const int tid  = threadIdx.x;
    const int lane = tid & 63;
    const int w    = tid >> 6;
    const int wm   = w >> 1, wn = w & 1;

    __shared__ __align__(16) short lA[2][128 * 32];   // 8KB each
    __shared__ __align__(16) short lB[2][128 * 32];

    f32x4 acc[4][4];
#pragma unroll
    for (int i = 0; i < 4; i++)
#pragma unroll
        for (int j = 0; j < 4; j++) acc[i][j] = (f32x4)(0.f);

    // staging: chunk c = w*2+p covers rows c*16..c*16+15; lane -> (row,slot)
    const int srow16 = lane >> 2;     // 0..15
    const int scg    = lane & 3;      // slot 0..3

#define PSTAGE(BUF, KC) {                                                     \
    const int k0_ = (KC) * 32;                                                \
    _Pragma("unroll")                                                         \
    for (int p = 0; p < 2; ++p) {                                             \
        int c = w * 2 + p;                                                    \
        int row = c * 16 + srow16;                                            \
        int kc = scg ^ ((row >> 1) & 3);                                      \
        gload_lds16(X + (size_t)(m0 + row) * DM + k0_ + kc * 8,               \
                    (char*)lA[BUF] + c * 1024);                               \
        gload_lds16(W + (size_t)(n0 + row) * DM + k0_ + kc * 8,               \
                    (char*)lB[BUF] + c * 1024);                               \
    } }

#define PCOMPUTE(BUF) {                                                       \
    s16x8 af[4], bf[4];                                                       \
    const int kq = lane >> 4;                                                 \
    _Pragma("unroll")                                                         \
    for (int i = 0; i < 4; i++) {                                             \
        int row = wm * 64 + i * 16 + (lane & 15);                             \
        int slot = kq ^ ((row >> 1) & 3);                                     \
        af[i] = *(const s16x8*)((const char*)lA[BUF] + row * 64 + slot * 16); \
    }                                                                         \
    _Pragma("unroll")                                                         \
    for (int i = 0; i < 4; i++) {                                             \
        int row = wn * 64 + i * 16 + (lane & 15);                             \
        int slot = kq ^ ((row >> 1) & 3);                                     \
        bf[i] = *(const s16x8*)((const char*)lB[BUF] + row * 64 + slot * 16); \
    }                                                                         \
    _Pragma("unroll")                                                         \
    for (int i = 0; i < 4; i++)                                               \
        _Pragma("unroll")                                                     \
        for (int j = 0; j < 4; j++)                                           \
            acc[i][j] = __builtin_amdgcn_mfma_f32_16x16x32_bf16(              \
                af[i], bf[j], acc[i][j], 0, 0, 0);                            \
    }

    PSTAGE(0, 0);
    __syncthreads();
    for (int kp = 0; kp < 16; ++kp) {
        const int k2 = kp * 2;
        if (k2 + 1 < 32) PSTAGE(1, k2 + 1);
        PCOMPUTE(0);
        __syncthreads();
        if (k2 + 2 < 32) PSTAGE(0, k2 + 2);
        PCOMPUTE(1);
        __syncthreads();
    }
#undef PSTAGE
#undef PCOMPUTE

#pragma unroll
    for (int i = 0; i < 4; i++) {
#pragma unroll
        for (int j = 0; j < 4; j++) {
            int rg0 = m0 + wm * 64 + i * 16 + 4 * (lane >> 4);
            int cg  = n0 + wn * 64 + j * 16 + (lane & 15);
            int b = rg0 >> 11, s0 = rg0 & 2047, h = cg >> 6, d = cg & 63;
            float bv_ = bias[cg];
            if (z == 2) {
                // kv column permute: swap bits 2<->3 (PV fragment order)
                int s0p = (s0 & ~12) | ((s0 & 4) << 1) | ((s0 & 8) >> 1);
                u16x4 st;
#pragma unroll
                for (int e = 0; e < 4; e++) st[e] = f2bf(acc[i][j][e] + bv_);
                *(u16x4*)&Vt[(((size_t)(b * NH + h)) * DKq + d) * SS + s0p] = st;
            } else if (z == 0) {
#pragma unroll
                for (int e = 0; e < 4; e++)
                    Qh[(((size_t)(b * NH + h)) * SS + s0 + e) * DKq + d] =
                        f2bf((acc[i][j][e] + bv_) * K2f);
            } else {
#pragma unroll
                for (int e = 0; e < 4; e++)
                    Kh[(((size_t)(b * NH + h)) * SS + s0 + e) * DKq + d] =
                        f2bf(acc[i][j][e] + bv_);
            }
        }
    }
}

// ---------------------------------------------------------------------------
// Kernel 2: flash attention, 32x32x16, KVBLK=128 windows, VALU row-sum.
// ---------------------------------------------------------------------------
__device__ __forceinline__ void attn_tile32(
    const char* __restrict__ lkc, const char* __restrict__ lvc,
    const s16x8* aq, int l31, int hi,
    f32x16& o0, f32x16& o1, float& rs)
{
    f32x16 s0 = (f32x16)(0.f), s1 = (f32x16)(0.f);
    const int sw = (l31 & 7) << 4;
    __builtin_amdgcn_s_setprio(1);
#pragma unroll
    for (int kkd = 0; kkd < 4; kkd++) {
        const int byte = (32 * kkd + 16 * hi) ^ sw;
        s16x8 ak0 = *(const s16x8*)(lkc + l31 * 128 + byte);
        s0 = __builtin_amdgcn_mfma_f32_32x32x16_bf16(ak0, aq[kkd], s0, 0, 0, 0);
        s16x8 ak1 = *(const s16x8*)(lkc + (32 + l31) * 128 + byte);
        s1 = __builtin_amdgcn_mfma_f32_32x32x16_bf16(ak1, aq[kkd], s1, 0, 0, 0);
    }
    __builtin_amdgcn_s_setprio(0);

    // P = exp2(s); per-lane partial row-sum (this lane's hi half of kv rows)
    float r0 = 0.f, r1 = 0.f;
#pragma unroll
    for (int r = 0; r < 16; r++) {
        float p0 = __builtin_amdgcn_exp2f(s0[r]);
        float p1 = __builtin_amdgcn_exp2f(s1[r]);
        s0[r] = p0; s1[r] = p1;
        r0 += p0; r1 += p1;
    }
    rs += r0 + r1;

    __builtin_amdgcn_s_setprio(1);
#pragma unroll
    for (int jb = 0; jb < 2; jb++) {
#pragma unroll
        for (int u = 0; u < 2; u++) {
            const int t = 2 * jb + u;
            union { unsigned uu[4]; s16x8 v; } bp;
            if (jb == 0) {
                bp.uu[0] = pkp(s0[8*u+0], s0[8*u+1]);
                bp.uu[1] = pkp(s0[8*u+2], s0[8*u+3]);
                bp.uu[2] = pkp(s0[8*u+4], s0[8*u+5]);
                bp.uu[3] = pkp(s0[8*u+6], s0[8*u+7]);
            } else {
                bp.uu[0] = pkp(s1[8*u+0], s1[8*u+1]);
                bp.uu[1] = pkp(s1[8*u+2], s1[8*u+3]);
                bp.uu[2] = pkp(s1[8*u+4], s1[8*u+5]);
                bp.uu[3] = pkp(s1[8*u+6], s1[8*u+7]);
            }
            const int vbyte = (32 * t + 16 * hi) ^ sw;
            s16x8 av0 = *(const s16x8*)(lvc + l31 * 128 + vbyte);
            o0 = __builtin_amdgcn_mfma_f32_32x32x16_bf16(av0, bp.v, o0, 0, 0, 0);
            s16x8 av1 = *(const s16x8*)(lvc + (32 + l31) * 128 + vbyte);
            o1 = __builtin_amdgcn_mfma_f32_32x32x16_bf16(av1, bp.v, o1, 0, 0, 0);
        }
    }
    __builtin_amdgcn_s_setprio(0);
}

__global__ __launch_bounds__(256)
void attn_kernel(const unsigned short* __restrict__ Qh,
                 const unsigned short* __restrict__ Kh,
                 const unsigned short* __restrict__ Vt,
                 unsigned short* __restrict__ Ctx)
{
    // XCD-chunked swizzle: 512 wgs, 64 per XCD -> 4 heads' K/V per XCD L2
    const int bid = blockIdx.x;
    const int tt  = (bid & 7) * 64 + (bid >> 3);
    const int bh  = tt >> 4;
    const int q0  = (tt & 15) * 128;

    const int tid = threadIdx.x, lane = tid & 63, w = tid >> 6;
    const int b = bh >> 4, h = bh & 15;
    const int l31 = lane & 31;
    const int hi  = lane >> 5;

    // each buffer = TWO 64-kv sub-tiles, concatenated (16KB K + 16KB V)
    __shared__ __align__(16) short lKs[2][128 * 64];
    __shared__ __align__(16) short lVs[2][128 * 64];

    const size_t qk_base = (size_t)bh * SS * DKq;
    const size_t vt_base = (size_t)bh * DKq * SS;

    // Q B-frag: col q = qrow, contraction d = 16*kkd + 8*hi + 0..7
    s16x8 aq[4];
    const int qrow = q0 + 32 * w + l31;
    {
        const unsigned short* qp = Qh + qk_base + (size_t)qrow * DKq + 8 * hi;
#pragma unroll
        for (int kkd = 0; kkd < 4; kkd++)
            aq[kkd] = *(const s16x8*)(qp + 16 * kkd);
    }

    f32x16 o0 = (f32x16)(0.f), o1 = (f32x16)(0.f);
    float rs = 0.f;

    // staging geometry (global_load_lds, pre-swizzled global source)
    const int lrow = lane >> 3;           // 0..7
    const int lcg  = (lane & 7) ^ lrow;   // inverse-swizzled col chunk

    // stage 128 kv rows (two 64-kv sub-tiles) per buffer; 4 chunks/thread
#define STAGE(BUF, KV0) {                                                     \
    char* dk = (char*)lKs[BUF]; char* dv = (char*)lVs[BUF];                   \
    _Pragma("unroll")                                                         \
    for (int p = 0; p < 4; ++p) {                                             \
        int c = 4 * w + p;            /* 0..15 */                             \
        int half = c >> 3, cc = c & 7;                                        \
        gload_lds16(Kh + qk_base + (size_t)((KV0) + c * 8 + lrow) * DKq + lcg * 8, \
                    dk + c * 1024);                                           \
        gload_lds16(Vt + vt_base + (size_t)(cc * 8 + lrow) * SS                \
                        + (KV0) + half * 64 + lcg * 8,                        \
                    dv + c * 1024);                                           \
    } }

    STAGE(0, 0);
    __syncthreads();

    for (int th = 0; th < 8; ++th) {
        const int T0 = th * 2;          // 128-kv tile index
        STAGE(1, (T0 + 1) * 128);
        attn_tile32((const char*)lKs[0], (const char*)lVs[0], aq, l31, hi, o0, o1, rs);
        attn_tile32((const char*)lKs[0] + 8192, (const char*)lVs[0] + 8192, aq, l31, hi, o0, o1, rs);
        __syncthreads();
        if (T0 + 2 < 16) STAGE(0, (T0 + 2) * 128);
        attn_tile32((const char*)lKs[1], (const char*)lVs[1], aq, l31, hi, o0, o1, rs);
        attn_tile32((const char*)lKs[1] + 8192, (const char*)lVs[1] + 8192, aq, l31, hi, o0, o1, rs);
        __syncthreads();
    }
#undef STAGE

    // epilogue: combine the two hi halves' partial sums, normalize, store
    rs += __shfl_xor(rs, 32);
    const float inv = 1.0f / rs;
    unsigned short* crow = Ctx + ((size_t)(b * SS + qrow)) * DM + h * 64;
#pragma unroll
    for (int db = 0; db < 2; db++) {
#pragma unroll
        for (int v = 0; v < 4; v++) {
            u16x4 st;
#pragma unroll
            for (int e = 0; e < 4; e++) {
                float x = (db == 0) ? o0[4 * v + e] : o1[4 * v + e];
                st[e] = f2bf(x * inv);
            }
            *(u16x4*)(crow + 32 * db + 8 * v + 4 * hi) = st;
        }
    }
}

// ---------------------------------------------------------------------------
// Kernel 3: out = Ctx @ Wo^T + bo + residual(Qh * 1/K2)  (fp32, into d_out)
// XCD-swizzled + 2-phase dbuf staging.
// ---------------------------------------------------------------------------
__global__ __launch_bounds__(256)
void outproj_kernel(const unsigned short* __restrict__ Ctx,
                    const unsigned short* __restrict__ Wo,
                    const float* __restrict__ bo,
                    const unsigned short* __restrict__ Qh,
                    float* __restrict__ Out)
{
    // XCD-chunked swizzle: 256 wgs, 32 per XCD
    const int bid = blockIdx.x;
    const int t   = (bid & 7) * 32 + (bid >> 3);
    const int ty  = t >> 3;
    const int tx  = t & 7;

    const int m0 = ty * 128;
    const int n0 = tx * 128;
    const int tid = threadIdx.x, lane = tid & 63, w = tid >> 6;
    const int wm = w >> 1, wn = w & 1;

    __shared__ __align__(16) short lA[2][128 * 64];
    __shared__ __align__(16) short lB[2][128 * 64];

    f32x4 acc[4][4];
#pragma unroll
    for (int i = 0; i < 4; i++)
#pragma unroll
        for (int j = 0; j < 4; j++) acc[i][j] = (f32x4)(0.f);

    const int lrow = lane >> 3;
    const int lcg  = (lane & 7) ^ lrow;

#define PSTAGE(BUF, KT) {                                                     \
    const int k0_ = (KT) * 64;                                                \
    _Pragma("unroll")                                                         \
    for (int p = 0; p < 4; ++p) {                                             \
        int c = w * 4 + p;                                                    \
        int row = c * 8 + lrow;                                               \
        gload_lds16(Ctx + (size_t)(m0 + row) * DM + k0_ + lcg * 8,            \
                    (char*)lA[BUF] + c * 1024);                               \
        gload_lds16(Wo + (size_t)(n0 + row) * DM + k0_ + lcg * 8,             \
                    (char*)lB[BUF] + c * 1024);                               \
    } }

#define PCOMPUTE(BUF) {                                                       \
    _Pragma("unroll")                                                         \
    for (int kk = 0; kk < 2; ++kk) {                                          \
        s16x8 af[4], bf[4];                                                   \
        _Pragma("unroll")                                                     \
        for (int i = 0; i < 4; i++) {                                         \
            int row = wm * 64 + i * 16 + (lane & 15);                         \
            int byte = (kk * 64 + 16 * (lane >> 4)) ^ ((row & 7) << 4);       \
            af[i] = *(const s16x8*)((const char*)lA[BUF] + row * 128 + byte); \
        }                                                                     \
        _Pragma("unroll")                                                     \
        for (int i = 0; i < 4; i++) {                                         \
            int row = wn * 64 + i * 16 + (lane & 15);                         \
            int byte = (kk * 64 + 16 * (lane >> 4)) ^ ((row & 7) << 4);       \
            bf[i] = *(const s16x8*)((const char*)lB[BUF] + row * 128 + byte); \
        }                                                                     \
        _Pragma("unroll")                                                     \
        for (int i = 0; i < 4; i++)                                           \
            _Pragma("unroll")                                                 \
            for (int j = 0; j < 4; j++)                                       \
                acc[i][j] = __builtin_amdgcn_mfma_f32_16x16x32_bf16(          \
                    af[i], bf[j], acc[i][j], 0, 0, 0);                        \
    } }

    PSTAGE(0, 0);
    __syncthreads();
    for (int kh = 0; kh < 8; ++kh) {
        const int k0 = kh * 2;
        if (k0 + 1 < 16) PSTAGE(1, k0 + 1);
        PCOMPUTE(0);
        __syncthreads();
        if (k0 + 2 < 16) PSTAGE(0, k0 + 2);
        PCOMPUTE(1);
        __syncthreads();
    }
#undef PSTAGE
#undef PCOMPUTE

#pragma unroll
    for (int i = 0; i < 4; i++) {
#pragma unroll
        for (int j = 0; j < 4; j++) {
            int rg0 = m0 + wm * 64 + i * 16 + 4 * (lane >> 4);
            int cg  = n0 + wn * 64 + j * 16 + (lane & 15);
            int b = rg0 >> 11, s0 = rg0 & 2047, h = cg >> 6, d = cg & 63;
            float bo_ = bo[cg];
#pragma unroll
            for (int e = 0; e < 4; e++) {
                float res = bf2f(Qh[(((size_t)(b * NH + h)) * SS + s0 + e) * DKq + d]);
                Out[(size_t)(rg0 + e) * DM + cg] =
                    __builtin_fmaf(res, IK2f, acc[i][j][e] + bo_);
            }
        }
    }
}

// ---------------------------------------------------------------------------
// Kernel 4: in-place LayerNorm over rows of Out [4096][1024]
// ---------------------------------------------------------------------------
__global__ __launch_bounds__(256)
void ln_kernel(float* __restrict__ Out, const float* __restrict__ gamma,
               const float* __restrict__ beta)
{
    const int row = blockIdx.x;
    float* rp = Out + (size_t)row * DM;
    const int tid = threadIdx.x;

    f32x4 x = *(const f32x4*)(rp + tid * 4);
    float s  = x[0] + x[1] + x[2] + x[3];
    float sq = x[0] * x[0] + x[1] * x[1] + x[2] * x[2] + x[3] * x[3];
#pragma unroll
    for (int off = 1; off < 64; off <<= 1) {
        s  += __shfl_xor(s, off);
        sq += __shfl_xor(sq, off);
    }
    __shared__ float ps[4], pq[4];
    const int w = tid >> 6;
    if ((tid & 63) == 0) { ps[w] = s; pq[w] = sq; }
    __syncthreads();
    float ts = ps[0] + ps[1] + ps[2] + ps[3];
    float tq = pq[0] + pq[1] + pq[2] + pq[3];
    float mu  = ts * (1.f / 1024.f);
    float var = tq * (1.f / 1024.f) - mu * mu;
    float rst = rsqrtf(var + 1e-5f);

    f32x4 g  = *(const f32x4*)(gamma + tid * 4);
    f32x4 bt = *(const f32x4*)(beta + tid * 4);
    f32x4 y;
#pragma unroll
    for (int e = 0; e < 4; e++) y[e] = (x[e] - mu) * rst * g[e] + bt[e];
    *(f32x4*)(rp + tid * 4) = y;
}

// ---------------------------------------------------------------------------
extern "C" void kernel_launch(void* const* d_in, const int* in_sizes, int n_in,
                              void* d_out, int out_size, void* d_ws, size_t ws_size,
                              hipStream_t stream)
{
    const float* query = (const float*)d_in[0];
    const float* key   = (const float*)d_in[1];
    const float* value = (const float*)d_in[2];
    const float* Wq = (const float*)d_in[3];
    const float* bq = (const float*)d_in[4];
    const float* Wk = (const float*)d_in[5];
    const float* bk = (const float*)d_in[6];
    const float* Wv = (const float*)d_in[7];
    const float* bv = (const float*)d_in[8];
    const float* Wo = (const float*)d_in[9];
    const float* bo = (const float*)d_in[10];
    const float* gamma = (const float*)d_in[11];
    const float* beta  = (const float*)d_in[12];

    char* ws = (char*)d_ws;
    // layout (56 MB total):
    //   Xb  @ 0      : 3 x 8MB bf16 activations (dead after proj)
    //   Wb  @ 24MB   : 4 x 2MB bf16 weights (q,k,v,o)
    //   Qh  @ 32MB, Kh @ 40MB, Vt @ 48MB : 8MB each
    //   Ctx @ 0      : 8MB, overlays dead Xb[query]
    unsigned short* Xb  = (unsigned short*)(ws);
    unsigned short* Wb  = (unsigned short*)(ws + (24u << 20));
    unsigned short* Qh  = (unsigned short*)(ws + (32u << 20));
    unsigned short* Kh  = (unsigned short*)(ws + (40u << 20));
    unsigned short* Vt  = (unsigned short*)(ws + (48u << 20));
    unsigned short* Ctx = (unsigned short*)(ws);
    float* Out = (float*)d_out;

    cvt_kernel<<<dim3(256, 7), 256, 0, stream>>>(query, key, value,
                                                 Wq, Wk, Wv, Wo, Xb, Wb);
    proj_kernel<<<768, 256, 0, stream>>>(Xb, Wb, bq, bk, bv, Qh, Kh, Vt);
    attn_kernel<<<512, 256, 0, stream>>>(Qh, Kh, Vt, Ctx);
    outproj_kernel<<<256, 256, 0, stream>>>(Ctx, Wb + 3u * DM * DM, bo, Qh, Out);
    ln_kernel<<<4096, 256, 0, stream>>>(Out, gamma, beta);
}